// Round 13
// baseline (227.134 us; speedup 1.0000x reference)
//
#include <hip/hip_runtime.h>
#include <stdint.h>
#include <stddef.h>

#define EMB 1024
#define NTOK 16384

typedef __attribute__((ext_vector_type(8))) short short8;
typedef __attribute__((ext_vector_type(4))) float floatx4;

__device__ __forceinline__ unsigned short f2bf(float f) {
    union { float f; unsigned int u; } v; v.f = f;
    unsigned int u = v.u;
    unsigned int r = (u + 0x7fffu + ((u >> 16) & 1u)) >> 16;
    return (unsigned short)r;
}
__device__ __forceinline__ float bf2f(unsigned short s) {
    union { unsigned int u; float f; } v; v.u = ((unsigned int)s) << 16;
    return v.f;
}

__device__ __forceinline__ void gload16(const void* g, void* l) {
    __builtin_amdgcn_global_load_lds(
        (const __attribute__((address_space(1))) void*)g,
        (__attribute__((address_space(3))) void*)l, 16, 0, 0);
}

#define SB0() __builtin_amdgcn_sched_barrier(0)

// ---------------- weights -> bf16 + bias concat, one dispatch ----------------
__global__ void cvtwb_kernel(const float* __restrict__ s0, const float* __restrict__ s1,
                             const float* __restrict__ s2, const float* __restrict__ s3,
                             const float* __restrict__ b0, const float* __restrict__ b1,
                             const float* __restrict__ b2,
                             unsigned short* __restrict__ out, float* __restrict__ bias_cat) {
    if (blockIdx.x == 0) {
#pragma unroll
        for (int t = 0; t < 12; ++t) {
            int i = t * 256 + threadIdx.x;
            float v = (i < 1024) ? b0[i] : (i < 2048 ? b1[i - 1024] : b2[i - 2048]);
            bias_cat[i] = v;
        }
    }
    int idx = blockIdx.x * blockDim.x + threadIdx.x;
    const int total = 4 << 18;
    int stride = gridDim.x * blockDim.x;
    for (int i = idx; i < total; i += stride) {
        int w = i >> 18, r = i & ((1 << 18) - 1);
        const float* s = (w == 0) ? s0 : (w == 1) ? s1 : (w == 2) ? s2 : s3;
        float4 f = reinterpret_cast<const float4*>(s)[r];
        ushort4 o;
        o.x = f2bf(f.x); o.y = f2bf(f.y); o.z = f2bf(f.z); o.w = f2bf(f.w);
        reinterpret_cast<ushort4*>(out)[i] = o;
    }
}

__device__ __forceinline__ void store_val(float* C, size_t idx, float v) { C[idx] = v; }
__device__ __forceinline__ void store_val(unsigned short* C, size_t idx, float v) { C[idx] = f2bf(v); }

// ------ QKV GEMM with FUSED fp32->bf16 A-staging (reg-staged A, T14 split) ------
// Geometry/sync = proven r11 kernel (256x256, BK=64, 512 thr, 128 KB dbuf LDS,
// XOR-swizzled granules, persistent multi-n blocks). A (fp32 src) is loaded to
// regs at region start, converted+ds_written AFTER the MFMA cluster; compiler's
// automatic vmcnt waits on the fp32 regs provide all VMEM draining needed for
// the B gload_lds pipeline (B issued after A-loads stays in flight; B issued in
// older regions is drained). vmcnt(2)+lgkmcnt(0) before each barrier are
// always-safe by counting (<=2 newest B loads may remain).
__global__ __launch_bounds__(512, 1)
void gemmA32(const float* __restrict__ Afp,
             const unsigned short* __restrict__ B,
             const float* __restrict__ bias,
             unsigned short* __restrict__ C,
             int Nc, int nt_n)
{
    __shared__ unsigned short lds[65536];  // 128 KB
    const int K = 1024;

    const int bid = blockIdx.x;            // grid = 256 = 8 XCD * 8 m * 4 ngrp
    const int x = bid & 7;
    const int w = bid >> 3;
    const int m0 = (x * 8 + (w & 7)) * 256;
    const int n_base = (w >> 3) * nt_n * 256;

    const int tid  = threadIdx.x;
    const int lane = tid & 63;
    const int wid  = tid >> 6;
    const int wm = (wid >> 2) * 128;
    const int wn = (wid & 3) * 64;
    const int rr = lane & 15;
    const int klo = (((lane >> 4) ^ ((rr >> 1) & 3)) << 3);

    const int aro = (wm + rr) * 32 + klo;
    const int bro = 16384 + (wn + rr) * 32 + klo;

    const float* pAf[2];
    const unsigned short* pB[2];
    int ldst[2];
#pragma unroll
    for (int l = 0; l < 2; ++l) {
        const int P16  = l * 512 + tid;
        const int rowS = P16 >> 2;
        const int colel = (((P16 & 3) ^ ((rowS >> 1) & 3)) << 3);
        pAf[l] = Afp + (size_t)(m0 + rowS) * K + colel;
        pB[l]  = B + (size_t)(n_base + rowS) * K + colel;
        ldst[l] = P16 * 8;
    }
    const size_t nstep = (size_t)256 * K;

    floatx4 acc[8][4];
#pragma unroll
    for (int i = 0; i < 8; ++i)
#pragma unroll
        for (int j = 0; j < 4; ++j)
            acc[i][j] = (floatx4){0.f, 0.f, 0.f, 0.f};

    const int NT = 16;
    const int TOT = nt_n * NT;

    // ---- prologue: A(t0) via load+cvt+write; B(t0) via gload_lds ----
#pragma unroll
    for (int l = 0; l < 2; ++l) {
#pragma unroll
        for (int kh = 0; kh < 2; ++kh) {
            float4 f0 = *reinterpret_cast<const float4*>(pAf[l] + kh * 32);
            float4 f1 = *reinterpret_cast<const float4*>(pAf[l] + kh * 32 + 4);
            short8 o;
            o[0] = (short)f2bf(f0.x); o[1] = (short)f2bf(f0.y);
            o[2] = (short)f2bf(f0.z); o[3] = (short)f2bf(f0.w);
            o[4] = (short)f2bf(f1.x); o[5] = (short)f2bf(f1.y);
            o[6] = (short)f2bf(f1.z); o[7] = (short)f2bf(f1.w);
            *reinterpret_cast<short8*>(&lds[kh * 8192 + ldst[l]]) = o;
        }
        gload16(pB[l],      &lds[16384 + ldst[l]]);
        gload16(pB[l] + 32, &lds[24576 + ldst[l]]);
    }
    asm volatile("s_waitcnt vmcnt(0)" ::: "memory");
    asm volatile("s_waitcnt lgkmcnt(0)" ::: "memory");
    asm volatile("s_barrier" ::: "memory");

    short8 a0[4], a1[4], b0[4];
#pragma unroll
    for (int i = 0; i < 4; ++i)
        a0[i] = *reinterpret_cast<const short8*>(&lds[aro + i * 512]);
#pragma unroll
    for (int j = 0; j < 4; ++j)
        b0[j] = *reinterpret_cast<const short8*>(&lds[bro + j * 512]);

    const int cn  = lane & 15;
    const int cm4 = (lane >> 4) * 4;

    for (int vt = 0; vt < TOT; ++vt) {
        const int cur = (vt & 1) * 32768;
        const int nxt = cur ^ 32768;
        int vtn = vt + 1; if (vtn == TOT) vtn = 0;
        const int ktn = (vtn & 15) * 64;
        const int nbn = vtn >> 4;
        const unsigned short* pBn0 = pB[0] + (size_t)nbn * nstep + ktn;
        const unsigned short* pBn1 = pB[1] + (size_t)nbn * nstep + ktn;

        // ============ region 1: kh0 ============
        float4 fA00 = *reinterpret_cast<const float4*>(pAf[0] + ktn);      // A-kh0(next)
        float4 fA01 = *reinterpret_cast<const float4*>(pAf[0] + ktn + 4);
        float4 fA10 = *reinterpret_cast<const float4*>(pAf[1] + ktn);
        float4 fA11 = *reinterpret_cast<const float4*>(pAf[1] + ktn + 4);
        gload16(pBn0, &lds[nxt + 16384 + ldst[0]]);                        // B-kh0(next)
        gload16(pBn1, &lds[nxt + 16384 + ldst[1]]);
#pragma unroll
        for (int i = 0; i < 4; ++i)
            a1[i] = *reinterpret_cast<const short8*>(&lds[cur + aro + 2048 + i * 512]);
        __builtin_amdgcn_s_setprio(1);
#pragma unroll
        for (int j = 0; j < 4; ++j)
#pragma unroll
            for (int i = 0; i < 4; ++i)
                acc[i][j] = __builtin_amdgcn_mfma_f32_16x16x32_bf16(a0[i], b0[j], acc[i][j], 0, 0, 0);
#pragma unroll
        for (int j = 0; j < 4; ++j)
#pragma unroll
            for (int i = 0; i < 4; ++i)
                acc[4 + i][j] = __builtin_amdgcn_mfma_f32_16x16x32_bf16(a1[i], b0[j], acc[4 + i][j], 0, 0, 0);
        __builtin_amdgcn_s_setprio(0);
        SB0();   // keep cvt+writes below the MFMA cluster (T14 split)
        {
            short8 o0, o1;
            o0[0] = (short)f2bf(fA00.x); o0[1] = (short)f2bf(fA00.y);
            o0[2] = (short)f2bf(fA00.z); o0[3] = (short)f2bf(fA00.w);
            o0[4] = (short)f2bf(fA01.x); o0[5] = (short)f2bf(fA01.y);
            o0[6] = (short)f2bf(fA01.z); o0[7] = (short)f2bf(fA01.w);
            o1[0] = (short)f2bf(fA10.x); o1[1] = (short)f2bf(fA10.y);
            o1[2] = (short)f2bf(fA10.z); o1[3] = (short)f2bf(fA10.w);
            o1[4] = (short)f2bf(fA11.x); o1[5] = (short)f2bf(fA11.y);
            o1[6] = (short)f2bf(fA11.z); o1[7] = (short)f2bf(fA11.w);
            *reinterpret_cast<short8*>(&lds[nxt + ldst[0]]) = o0;
            *reinterpret_cast<short8*>(&lds[nxt + ldst[1]]) = o1;
        }
        asm volatile("s_waitcnt vmcnt(2)" ::: "memory");
        asm volatile("s_waitcnt lgkmcnt(0)" ::: "memory");
        asm volatile("s_barrier" ::: "memory");

        // ============ region 2: kh1 ============
        fA00 = *reinterpret_cast<const float4*>(pAf[0] + ktn + 32);        // A-kh1(next)
        fA01 = *reinterpret_cast<const float4*>(pAf[0] + ktn + 36);
        fA10 = *reinterpret_cast<const float4*>(pAf[1] + ktn + 32);
        fA11 = *reinterpret_cast<const float4*>(pAf[1] + ktn + 36);
        gload16(pBn0 + 32, &lds[nxt + 24576 + ldst[0]]);                   // B-kh1(next)
        gload16(pBn1 + 32, &lds[nxt + 24576 + ldst[1]]);
#pragma unroll
        for (int i = 0; i < 4; ++i)
            a0[i] = *reinterpret_cast<const short8*>(&lds[cur + 8192 + aro + i * 512]);
#pragma unroll
        for (int j = 0; j < 4; ++j)
            b0[j] = *reinterpret_cast<const short8*>(&lds[cur + 8192 + bro + j * 512]);
#pragma unroll
        for (int i = 0; i < 4; ++i)
            a1[i] = *reinterpret_cast<const short8*>(&lds[cur + 8192 + aro + 2048 + i * 512]);
        __builtin_amdgcn_s_setprio(1);
#pragma unroll
        for (int j = 0; j < 4; ++j)
#pragma unroll
            for (int i = 0; i < 4; ++i)
                acc[i][j] = __builtin_amdgcn_mfma_f32_16x16x32_bf16(a0[i], b0[j], acc[i][j], 0, 0, 0);
#pragma unroll
        for (int j = 0; j < 4; ++j)
#pragma unroll
            for (int i = 0; i < 4; ++i)
                acc[4 + i][j] = __builtin_amdgcn_mfma_f32_16x16x32_bf16(a1[i], b0[j], acc[4 + i][j], 0, 0, 0);
        __builtin_amdgcn_s_setprio(0);
        SB0();
        {
            short8 o0, o1;
            o0[0] = (short)f2bf(fA00.x); o0[1] = (short)f2bf(fA00.y);
            o0[2] = (short)f2bf(fA00.z); o0[3] = (short)f2bf(fA00.w);
            o0[4] = (short)f2bf(fA01.x); o0[5] = (short)f2bf(fA01.y);
            o0[6] = (short)f2bf(fA01.z); o0[7] = (short)f2bf(fA01.w);
            o1[0] = (short)f2bf(fA10.x); o1[1] = (short)f2bf(fA10.y);
            o1[2] = (short)f2bf(fA10.z); o1[3] = (short)f2bf(fA10.w);
            o1[4] = (short)f2bf(fA11.x); o1[5] = (short)f2bf(fA11.y);
            o1[6] = (short)f2bf(fA11.z); o1[7] = (short)f2bf(fA11.w);
            *reinterpret_cast<short8*>(&lds[nxt + 8192 + ldst[0]]) = o0;
            *reinterpret_cast<short8*>(&lds[nxt + 8192 + ldst[1]]) = o1;
        }
        asm volatile("s_waitcnt vmcnt(2)" ::: "memory");
        asm volatile("s_waitcnt lgkmcnt(0)" ::: "memory");
        asm volatile("s_barrier" ::: "memory");
        // read-ahead next tile's kh0 fragments
#pragma unroll
        for (int i = 0; i < 4; ++i)
            a0[i] = *reinterpret_cast<const short8*>(&lds[nxt + aro + i * 512]);
#pragma unroll
        for (int j = 0; j < 4; ++j)
            b0[j] = *reinterpret_cast<const short8*>(&lds[nxt + bro + j * 512]);

        // ---- per-n epilogue ----
        if ((vt & 15) == 15) {
            const int n0 = n_base + (vt >> 4) * 256;
            float bv[4];
#pragma unroll
            for (int j = 0; j < 4; ++j) bv[j] = bias[n0 + wn + j * 16 + cn];
#pragma unroll
            for (int ai = 0; ai < 8; ++ai) {
                const int row = m0 + wm + (ai >> 2) * 64 + (ai & 3) * 16 + cm4;
#pragma unroll
                for (int j = 0; j < 4; ++j) {
                    const int col = n0 + wn + j * 16 + cn;
#pragma unroll
                    for (int r = 0; r < 4; ++r)
                        C[(size_t)(row + r) * Nc + col] = f2bf(acc[ai][j][r] + bv[j]);
                }
            }
#pragma unroll
            for (int i = 0; i < 8; ++i)
#pragma unroll
                for (int j = 0; j < 4; ++j)
                    acc[i][j] = (floatx4){0.f, 0.f, 0.f, 0.f};
        }
    }
}

// ------- r11's proven bf16-A GEMM (unchanged) for the O-projection -------
template<typename OUT_T>
__global__ __launch_bounds__(512, 1)
void gemm256mn(const unsigned short* __restrict__ A,
               const unsigned short* __restrict__ B,
               const float* __restrict__ bias,
               OUT_T* __restrict__ C,
               int Nc, int nt_n)
{
    __shared__ unsigned short lds[65536];
    const int K = 1024;
    const int NT = 16;

    const int bid = blockIdx.x;
    const int x = bid & 7;
    const int w = bid >> 3;
    const int m0 = (x * 8 + (w & 7)) * 256;
    const int n_base = (w >> 3) * nt_n * 256;

    const int tid  = threadIdx.x;
    const int lane = tid & 63;
    const int wid  = tid >> 6;
    const int wm = (wid >> 2) * 128;
    const int wn = (wid & 3) * 64;
    const int rr = lane & 15;
    const int klo = (((lane >> 4) ^ ((rr >> 1) & 3)) << 3);

    const int aro = (wm + rr) * 32 + klo;
    const int bro = 16384 + (wn + rr) * 32 + klo;

    const unsigned short* pA[2];
    const unsigned short* pB[2];
    int ldst[2];
#pragma unroll
    for (int l = 0; l < 2; ++l) {
        const int P16  = l * 512 + tid;
        const int rowS = P16 >> 2;
        const int colel = (((P16 & 3) ^ ((rowS >> 1) & 3)) << 3);
        pA[l] = A + (size_t)(m0 + rowS) * K + colel;
        pB[l] = B + (size_t)(n_base + rowS) * K + colel;
        ldst[l] = P16 * 8;
    }
    const size_t nstep = (size_t)256 * K;

    floatx4 acc[8][4];
#pragma unroll
    for (int i = 0; i < 8; ++i)
#pragma unroll
        for (int j = 0; j < 4; ++j)
            acc[i][j] = (floatx4){0.f, 0.f, 0.f, 0.f};

    const int TOT = nt_n * NT;

#pragma unroll
    for (int l = 0; l < 2; ++l) {
        gload16(pA[l],      &lds[0     + ldst[l]]);
        gload16(pA[l] + 32, &lds[8192  + ldst[l]]);
        gload16(pB[l],      &lds[16384 + ldst[l]]);
        gload16(pB[l] + 32, &lds[24576 + ldst[l]]);
    }
    asm volatile("s_waitcnt vmcnt(0)" ::: "memory");
    asm volatile("s_barrier" ::: "memory");

    short8 a0[4], a1[4], b0[4];
#pragma unroll
    for (int i = 0; i < 4; ++i)
        a0[i] = *reinterpret_cast<const short8*>(&lds[aro + i * 512]);
#pragma unroll
    for (int j = 0; j < 4; ++j)
        b0[j] = *reinterpret_cast<const short8*>(&lds[bro + j * 512]);

    const int cn  = lane & 15;
    const int cm4 = (lane >> 4) * 4;

    for (int vt = 0; vt < TOT; ++vt) {
        const int cur = (vt & 1) * 32768;
        const int nxt = cur ^ 32768;
        int vtn = vt + 1; if (vtn == TOT) vtn = 0;
        const int ktn = (vtn & 15) * 64;
        const int nbn = vtn >> 4;
        const unsigned short* pBn0 = pB[0] + (size_t)nbn * nstep + ktn;
        const unsigned short* pBn1 = pB[1] + (size_t)nbn * nstep + ktn;

        gload16(pA[0] + ktn, &lds[nxt + ldst[0]]);
        gload16(pA[1] + ktn, &lds[nxt + ldst[1]]);
        gload16(pBn0,        &lds[nxt + 16384 + ldst[0]]);
        gload16(pBn1,        &lds[nxt + 16384 + ldst[1]]);
#pragma unroll
        for (int i = 0; i < 4; ++i)
            a1[i] = *reinterpret_cast<const short8*>(&lds[cur + aro + 2048 + i * 512]);
        __builtin_amdgcn_s_setprio(1);
#pragma unroll
        for (int j = 0; j < 4; ++j)
#pragma unroll
            for (int i = 0; i < 4; ++i)
                acc[i][j] = __builtin_amdgcn_mfma_f32_16x16x32_bf16(a0[i], b0[j], acc[i][j], 0, 0, 0);
#pragma unroll
        for (int j = 0; j < 4; ++j)
#pragma unroll
            for (int i = 0; i < 4; ++i)
                acc[4 + i][j] = __builtin_amdgcn_mfma_f32_16x16x32_bf16(a1[i], b0[j], acc[4 + i][j], 0, 0, 0);
        __builtin_amdgcn_s_setprio(0);
        asm volatile("s_waitcnt vmcnt(4)" ::: "memory");
        asm volatile("s_barrier" ::: "memory");

        gload16(pA[0] + ktn + 32, &lds[nxt + 8192 + ldst[0]]);
        gload16(pA[1] + ktn + 32, &lds[nxt + 8192 + ldst[1]]);
        gload16(pBn0 + 32,        &lds[nxt + 24576 + ldst[0]]);
        gload16(pBn1 + 32,        &lds[nxt + 24576 + ldst[1]]);
#pragma unroll
        for (int i = 0; i < 4; ++i)
            a0[i] = *reinterpret_cast<const short8*>(&lds[cur + 8192 + aro + i * 512]);
#pragma unroll
        for (int j = 0; j < 4; ++j)
            b0[j] = *reinterpret_cast<const short8*>(&lds[cur + 8192 + bro + j * 512]);
#pragma unroll
        for (int i = 0; i < 4; ++i)
            a1[i] = *reinterpret_cast<const short8*>(&lds[cur + 8192 + aro + 2048 + i * 512]);
        __builtin_amdgcn_s_setprio(1);
#pragma unroll
        for (int j = 0; j < 4; ++j)
#pragma unroll
            for (int i = 0; i < 4; ++i)
                acc[i][j] = __builtin_amdgcn_mfma_f32_16x16x32_bf16(a0[i], b0[j], acc[i][j], 0, 0, 0);
#pragma unroll
        for (int j = 0; j < 4; ++j)
#pragma unroll
            for (int i = 0; i < 4; ++i)
                acc[4 + i][j] = __builtin_amdgcn_mfma_f32_16x16x32_bf16(a1[i], b0[j], acc[4 + i][j], 0, 0, 0);
        __builtin_amdgcn_s_setprio(0);
        asm volatile("s_waitcnt vmcnt(4)" ::: "memory");
        asm volatile("s_barrier" ::: "memory");
#pragma unroll
        for (int i = 0; i < 4; ++i)
            a0[i] = *reinterpret_cast<const short8*>(&lds[nxt + aro + i * 512]);
#pragma unroll
        for (int j = 0; j < 4; ++j)
            b0[j] = *reinterpret_cast<const short8*>(&lds[nxt + bro + j * 512]);

        if ((vt & 15) == 15) {
            const int n0 = n_base + (vt >> 4) * 256;
            float bv[4];
#pragma unroll
            for (int j = 0; j < 4; ++j) bv[j] = bias[n0 + wn + j * 16 + cn];
#pragma unroll
            for (int ai = 0; ai < 8; ++ai) {
                const int row = m0 + wm + (ai >> 2) * 64 + (ai & 3) * 16 + cm4;
#pragma unroll
                for (int j = 0; j < 4; ++j) {
                    const int col = n0 + wn + j * 16 + cn;
#pragma unroll
                    for (int r = 0; r < 4; ++r)
                        store_val(C, (size_t)(row + r) * Nc + col, acc[ai][j][r] + bv[j]);
                }
            }
#pragma unroll
            for (int i = 0; i < 8; ++i)
#pragma unroll
                for (int j = 0; j < 4; ++j)
                    acc[i][j] = (floatx4){0.f, 0.f, 0.f, 0.f};
        }
    }
}

// ---------------- per-token 16-head attention (wave per token) ----------------
#define ROWP 72

__global__ __launch_bounds__(256)
void attn_kernel(const unsigned short* __restrict__ QKV,
                 unsigned short* __restrict__ O)
{
    const int wave = threadIdx.x >> 6;
    const int lane = threadIdx.x & 63;
    const int n = blockIdx.x * 4 + wave;

    __shared__ unsigned short lq[4][16 * ROWP];
    __shared__ unsigned short lk[4][16 * ROWP];
    __shared__ unsigned short lv[4][16 * ROWP];
    __shared__ float lp[4][256];

    {
        const unsigned short* gq = QKV + (size_t)n * 3072;
        const unsigned short* gk = gq + 1024;
        const unsigned short* gv = gq + 2048;
        for (int t = lane; t < 128; t += 64) {
            int r = t >> 3, c = t & 7;
            *reinterpret_cast<short8*>(&lq[wave][r * ROWP + c * 8]) =
                *reinterpret_cast<const short8*>(gq + t * 8);
            *reinterpret_cast<short8*>(&lk[wave][r * ROWP + c * 8]) =
                *reinterpret_cast<const short8*>(gk + t * 8);
            *reinterpret_cast<short8*>(&lv[wave][r * ROWP + c * 8]) =
                *reinterpret_cast<const short8*>(gv + t * 8);
        }
    }
    __syncthreads();

    const int g = lane & 15;
    const int a = lane >> 4;

    float kf[64];
#pragma unroll
    for (int c2 = 0; c2 < 8; ++c2) {
        short8 kv = *reinterpret_cast<const short8*>(&lk[wave][g * ROWP + c2 * 8]);
#pragma unroll
        for (int e = 0; e < 8; ++e) kf[c2 * 8 + e] = bf2f((unsigned short)kv[e]);
    }

#pragma unroll
    for (int i = 0; i < 4; ++i) {
        const int h = i * 4 + a;
        float s = 0.f;
#pragma unroll
        for (int c2 = 0; c2 < 8; ++c2) {
            short8 qv = *reinterpret_cast<const short8*>(&lq[wave][h * ROWP + c2 * 8]);
#pragma unroll
            for (int e = 0; e < 8; ++e)
                s = fmaf(bf2f((unsigned short)qv[e]), kf[c2 * 8 + e], s);
        }
        s *= 0.125f;

        float m = s;
#pragma unroll
        for (int o = 1; o < 16; o <<= 1) m = fmaxf(m, __shfl_xor(m, o, 64));
        float p = expf(s - m);
        float sum = p;
#pragma unroll
        for (int o = 1; o < 16; o <<= 1) sum += __shfl_xor(sum, o, 64);
        lp[wave][h * 16 + g] = p / sum;
    }
    __syncthreads();

    const int h = lane >> 2;
    const int db = (lane & 3) * 16;
    float o[16];
#pragma unroll
    for (int e = 0; e < 16; ++e) o[e] = 0.f;

    for (int g2 = 0; g2 < 16; ++g2) {
        const float pw = lp[wave][h * 16 + g2];
        short8 v0 = *reinterpret_cast<const short8*>(&lv[wave][g2 * ROWP + db]);
        short8 v1 = *reinterpret_cast<const short8*>(&lv[wave][g2 * ROWP + db + 8]);
#pragma unroll
        for (int e = 0; e < 8; ++e) {
            o[e]     = fmaf(pw, bf2f((unsigned short)v0[e]), o[e]);
            o[8 + e] = fmaf(pw, bf2f((unsigned short)v1[e]), o[8 + e]);
        }
    }

    short8 o0, o1;
#pragma unroll
    for (int e = 0; e < 8; ++e) {
        o0[e] = (short)f2bf(o[e]);
        o1[e] = (short)f2bf(o[8 + e]);
    }
    unsigned short* dst = O + (size_t)n * EMB + h * 64 + db;
    *reinterpret_cast<short8*>(dst) = o0;
    *reinterpret_cast<short8*>(dst + 8) = o1;
}

// ---------------- launch ----------------
extern "C" void kernel_launch(void* const* d_in, const int* in_sizes, int n_in,
                              void* d_out, int out_size, void* d_ws, size_t ws_size,
                              hipStream_t stream)
{
    const float* src = (const float*)d_in[0];
    const float* Wq  = (const float*)d_in[1];
    const float* bq  = (const float*)d_in[2];
    const float* Wk  = (const float*)d_in[3];
    const float* bk  = (const float*)d_in[4];
    const float* Wv  = (const float*)d_in[5];
    const float* bv  = (const float*)d_in[6];
    const float* Wo  = (const float*)d_in[7];
    const float* bo  = (const float*)d_in[8];
    float* out = (float*)d_out;

    unsigned short* ws = (unsigned short*)d_ws;
    unsigned short* wqkv   = ws;                                      // 3*1024*1024 (Wq|Wk|Wv)
    unsigned short* wo_bf  = wqkv + (size_t)3 * EMB * EMB;            // 1024*1024
    unsigned short* qkv    = wo_bf + (size_t)EMB * EMB;               // 16384*3072
    unsigned short* ab     = qkv + (size_t)NTOK * 3 * EMB;            // 16384*1024
    float* bias_cat        = (float*)(ab + (size_t)NTOK * EMB);       // 3072 floats

    cvtwb_kernel<<<2048, 256, 0, stream>>>(Wq, Wk, Wv, Wo, bq, bk, bv, wqkv, bias_cat);

    // fused QKV projection with inline fp32->bf16 A-staging
    gemmA32<<<dim3(256), 512, 0, stream>>>(src, wqkv, bias_cat, qkv, 3 * EMB, 3);

    attn_kernel<<<NTOK / 4, 256, 0, stream>>>(qkv, ab);

    // output projection
    gemm256mn<float><<<dim3(256), 512, 0, stream>>>(ab, wo_bf, bo, out, EMB, 1);
}

// Round 14
// 195.832 us; speedup vs baseline: 1.1598x; 1.1598x over previous
//
#include <hip/hip_runtime.h>
#include <stdint.h>
#include <stddef.h>

#define EMB 1024
#define NTOK 16384

typedef __attribute__((ext_vector_type(8))) short short8;
typedef __attribute__((ext_vector_type(4))) float floatx4;

__device__ __forceinline__ unsigned short f2bf(float f) {
    union { float f; unsigned int u; } v; v.f = f;
    unsigned int u = v.u;
    unsigned int r = (u + 0x7fffu + ((u >> 16) & 1u)) >> 16;
    return (unsigned short)r;
}
__device__ __forceinline__ float bf2f(unsigned short s) {
    union { unsigned int u; float f; } v; v.u = ((unsigned int)s) << 16;
    return v.f;
}

__device__ __forceinline__ void gload16(const void* g, void* l) {
    __builtin_amdgcn_global_load_lds(
        (const __attribute__((address_space(1))) void*)g,
        (__attribute__((address_space(3))) void*)l, 16, 0, 0);
}

#define SB0() __builtin_amdgcn_sched_barrier(0)

// opaque LDS b128 read: base VGPR (bytes) + compile-time immediate offset
#define DSR(dst, base, imm) \
    asm volatile("ds_read_b128 %0, %1 offset:%c2" : "=&v"(dst) : "v"(base), "i"(imm))

// ------- ALL conversions in ONE dispatch: src->bf16, 4 weights->bf16, bias cat -------
__global__ void cvt_all(const float* __restrict__ src,
                        const float* __restrict__ s0, const float* __restrict__ s1,
                        const float* __restrict__ s2, const float* __restrict__ s3,
                        const float* __restrict__ b0, const float* __restrict__ b1,
                        const float* __restrict__ b2,
                        unsigned short* __restrict__ src_bf,
                        unsigned short* __restrict__ wout,
                        float* __restrict__ bias_cat) {
    if (blockIdx.x == 0) {
#pragma unroll
        for (int t = 0; t < 12; ++t) {
            int i = t * 256 + threadIdx.x;
            float v = (i < 1024) ? b0[i] : (i < 2048 ? b1[i - 1024] : b2[i - 2048]);
            bias_cat[i] = v;
        }
    }
    const int SRC4 = 1 << 22;              // src granules (float4)
    const int TOT4 = SRC4 + (1 << 20);     // + weight granules
    int idx = blockIdx.x * blockDim.x + threadIdx.x;
    int stride = gridDim.x * blockDim.x;
    for (int i = idx; i < TOT4; i += stride) {
        const float* sp;
        unsigned short* op;
        int r;
        if (i < SRC4) {
            sp = src; op = src_bf; r = i;
        } else {
            int j = i - SRC4;
            int w = j >> 18; r = j & ((1 << 18) - 1);
            sp = (w == 0) ? s0 : (w == 1) ? s1 : (w == 2) ? s2 : s3;
            op = wout + ((size_t)(i - SRC4) & ~((size_t)(1 << 18) - 1)) * 4;  // w * 2^20 elems
        }
        float4 f = reinterpret_cast<const float4*>(sp)[r];
        ushort4 o;
        o.x = f2bf(f.x); o.y = f2bf(f.y); o.z = f2bf(f.z); o.w = f2bf(f.w);
        reinterpret_cast<ushort4*>(op)[r] = o;
    }
}

// ---------------- 256x256 8-phase bf16 GEMM (r10, verified) ----------------
__device__ __forceinline__ void store_val(float* C, size_t idx, float v) { C[idx] = v; }
__device__ __forceinline__ void store_val(unsigned short* C, size_t idx, float v) { C[idx] = f2bf(v); }

#define STG_A(h, bf, ko) do { \
    gload16(pA + (h)*KH + (ko),       &lds[(bf)*32768 + (h)*8192 + ldT]);  \
    gload16(pA + (h)*KH + (ko) + K64, &lds[(bf)*32768 + (h)*8192 + ldT2]); } while (0)
#define STG_B(h, bf, ko) do { \
    gload16(pB + (h)*KH + (ko),       &lds[(bf)*32768 + 16384 + (h)*8192 + ldT]);  \
    gload16(pB + (h)*KH + (ko) + K64, &lds[(bf)*32768 + 16384 + (h)*8192 + ldT2]); } while (0)

#define QMFMA(MB, NB, BF) do { \
    _Pragma("unroll") \
    for (int j_ = 0; j_ < 2; ++j_) { \
        _Pragma("unroll") \
        for (int i_ = 0; i_ < 4; ++i_) { \
            acc[(MB)+i_][(NB)+j_] = __builtin_amdgcn_mfma_f32_16x16x32_bf16(ak0[i_], BF[j_*2],   acc[(MB)+i_][(NB)+j_], 0, 0, 0); \
            acc[(MB)+i_][(NB)+j_] = __builtin_amdgcn_mfma_f32_16x16x32_bf16(ak1[i_], BF[j_*2+1], acc[(MB)+i_][(NB)+j_], 0, 0, 0); \
        } } } while (0)

template<typename OUT_T>
__global__ __launch_bounds__(512, 1)
void gemm8p(const unsigned short* __restrict__ A,
            const unsigned short* __restrict__ B,
            const float* __restrict__ bias,
            OUT_T* __restrict__ C,
            int K, int Nc, int grid_m)
{
    __shared__ unsigned short lds[65536];  // 128 KB

    const int bid = blockIdx.x;
    const int x = bid & 7;
    const int w = bid >> 3;
    const int ms = grid_m >> 3;
    const int m0 = (x * ms + (w & (ms - 1))) * 256;
    const int n0 = (w / ms) * 256;

    const int tid = threadIdx.x, lane = tid & 63, wid = tid >> 6;
    const int wm = (wid >> 2) * 128, wn = (wid & 3) * 64;
    const int rr = lane & 15, ls = lane >> 4;
    const int sw0 = ((ls)     ^ (rr & 7)) << 4;
    const int sw1 = ((4 | ls) ^ (rr & 7)) << 4;

    const unsigned ldsb = (unsigned)(uintptr_t)(void*)&lds[0];
    const unsigned aB0 = ldsb + (unsigned)((wm >> 7) * 16384 + rr * 128 + sw0);
    const unsigned aB1 = ldsb + (unsigned)((wm >> 7) * 16384 + rr * 128 + sw1);
    const unsigned bB0 = ldsb + 32768u + (unsigned)((wn >> 7) * 16384 + (wn & 64) * 128 + rr * 128 + sw0);
    const unsigned bB1 = ldsb + 32768u + (unsigned)((wn >> 7) * 16384 + (wn & 64) * 128 + rr * 128 + sw1);

    const int rT = tid >> 3, gst = tid & 7;
    const int gsrc = (gst ^ (rT & 7)) * 8;
    const unsigned short* pA = A + (size_t)(m0 + rT) * K + gsrc;
    const unsigned short* pB = B + (size_t)(n0 + rT) * K + gsrc;
    const int K64 = K * 64, KH = K * 128;
    const int ldT = tid * 8, ldT2 = (tid + 512) * 8;

    floatx4 acc[8][4];
#pragma unroll
    for (int i = 0; i < 8; ++i)
#pragma unroll
        for (int j = 0; j < 4; ++j)
            acc[i][j] = (floatx4){0.f, 0.f, 0.f, 0.f};

    const int NT = K >> 6;

    STG_A(0, 0, 0); STG_A(1, 0, 0); STG_B(0, 0, 0); STG_B(1, 0, 0);
    STG_B(0, 1, 64); STG_B(1, 1, 64);
    SB0();
    asm volatile("s_waitcnt vmcnt(4)");
    __builtin_amdgcn_s_barrier();
    SB0();

    short8 ak0[4], ak1[4], b0f[4], b1f[4];

    for (int t = 0; t < NT; ++t) {
        const int bfc = t & 1, bfn = bfc ^ 1;
        const unsigned cB = (unsigned)(bfc * 65536);
        const unsigned aC0 = aB0 + cB, aC1 = aB1 + cB;
        const unsigned bC0 = bB0 + cB, bC1 = bB1 + cB;
        const int ko1 = ((t + 1 < NT) ? (t + 1) : 0) * 64;
        const int ko2 = ((t + 2 < NT) ? (t + 2) : (t + 2 - NT)) * 64;

        // ===== ph0 =====
        DSR(ak0[0], aC0, 0);    DSR(ak0[1], aC0, 2048);
        DSR(ak0[2], aC0, 4096); DSR(ak0[3], aC0, 6144);
        DSR(ak1[0], aC1, 0);    DSR(ak1[1], aC1, 2048);
        DSR(ak1[2], aC1, 4096); DSR(ak1[3], aC1, 6144);
        DSR(b0f[0], bC0, 0);    DSR(b0f[1], bC1, 0);
        DSR(b0f[2], bC0, 2048); DSR(b0f[3], bC1, 2048);
        STG_A(0, bfn, ko1);
        SB0();
        __builtin_amdgcn_s_barrier();
        asm volatile("s_waitcnt lgkmcnt(0)");
        SB0();
        __builtin_amdgcn_s_setprio(1);
        QMFMA(0, 0, b0f);
        __builtin_amdgcn_s_setprio(0);
        SB0();
        __builtin_amdgcn_s_barrier();
        SB0();

        // ===== ph1 =====
        DSR(b1f[0], bC0, 4096); DSR(b1f[1], bC1, 4096);
        DSR(b1f[2], bC0, 6144); DSR(b1f[3], bC1, 6144);
        STG_A(1, bfn, ko1);
        SB0();
        __builtin_amdgcn_s_barrier();
        asm volatile("s_waitcnt lgkmcnt(0)");
        SB0();
        __builtin_amdgcn_s_setprio(1);
        QMFMA(0, 2, b1f);
        __builtin_amdgcn_s_setprio(0);
        SB0();
        __builtin_amdgcn_s_barrier();
        SB0();

        // ===== ph2 =====
        DSR(ak0[0], aC0, 8192);  DSR(ak0[1], aC0, 10240);
        DSR(ak0[2], aC0, 12288); DSR(ak0[3], aC0, 14336);
        DSR(ak1[0], aC1, 8192);  DSR(ak1[1], aC1, 10240);
        DSR(ak1[2], aC1, 12288); DSR(ak1[3], aC1, 14336);
        STG_B(0, bfc, ko2);
        SB0();
        __builtin_amdgcn_s_barrier();
        asm volatile("s_waitcnt lgkmcnt(0)");
        SB0();
        __builtin_amdgcn_s_setprio(1);
        QMFMA(4, 2, b1f);
        __builtin_amdgcn_s_setprio(0);
        SB0();
        __builtin_amdgcn_s_barrier();
        SB0();

        // ===== ph3 =====
        STG_B(1, bfc, ko2);
        SB0();
        __builtin_amdgcn_s_barrier();
        SB0();
        __builtin_amdgcn_s_setprio(1);
        QMFMA(4, 0, b0f);
        __builtin_amdgcn_s_setprio(0);
        SB0();
        asm volatile("s_waitcnt vmcnt(4)");
        __builtin_amdgcn_s_barrier();
        SB0();
    }

    const int cn  = lane & 15;
    const int cm4 = (lane >> 4) * 4;
    float bv[4];
#pragma unroll
    for (int j = 0; j < 4; ++j) bv[j] = bias[n0 + wn + j * 16 + cn];
#pragma unroll
    for (int ai = 0; ai < 8; ++ai) {
        const int row = m0 + wm + (ai >> 2) * 64 + (ai & 3) * 16 + cm4;
#pragma unroll
        for (int j = 0; j < 4; ++j) {
            const int col = n0 + wn + j * 16 + cn;
#pragma unroll
            for (int r = 0; r < 4; ++r)
                store_val(C, (size_t)(row + r) * Nc + col, acc[ai][j][r] + bv[j]);
        }
    }
}

// ---------------- per-token 16-head attention (wave per token) ----------------
#define ROWP 72

__global__ __launch_bounds__(256)
void attn_kernel(const unsigned short* __restrict__ QKV,
                 unsigned short* __restrict__ O)
{
    const int wave = threadIdx.x >> 6;
    const int lane = threadIdx.x & 63;
    const int n = blockIdx.x * 4 + wave;

    __shared__ unsigned short lq[4][16 * ROWP];
    __shared__ unsigned short lk[4][16 * ROWP];
    __shared__ unsigned short lv[4][16 * ROWP];
    __shared__ float lp[4][256];

    {
        const unsigned short* gq = QKV + (size_t)n * 3072;
        const unsigned short* gk = gq + 1024;
        const unsigned short* gv = gq + 2048;
        for (int t = lane; t < 128; t += 64) {
            int r = t >> 3, c = t & 7;
            *reinterpret_cast<short8*>(&lq[wave][r * ROWP + c * 8]) =
                *reinterpret_cast<const short8*>(gq + t * 8);
            *reinterpret_cast<short8*>(&lk[wave][r * ROWP + c * 8]) =
                *reinterpret_cast<const short8*>(gk + t * 8);
            *reinterpret_cast<short8*>(&lv[wave][r * ROWP + c * 8]) =
                *reinterpret_cast<const short8*>(gv + t * 8);
        }
    }
    __syncthreads();

    const int g = lane & 15;
    const int a = lane >> 4;

    float kf[64];
#pragma unroll
    for (int c2 = 0; c2 < 8; ++c2) {
        short8 kv = *reinterpret_cast<const short8*>(&lk[wave][g * ROWP + c2 * 8]);
#pragma unroll
        for (int e = 0; e < 8; ++e) kf[c2 * 8 + e] = bf2f((unsigned short)kv[e]);
    }

#pragma unroll
    for (int i = 0; i < 4; ++i) {
        const int h = i * 4 + a;
        float s = 0.f;
#pragma unroll
        for (int c2 = 0; c2 < 8; ++c2) {
            short8 qv = *reinterpret_cast<const short8*>(&lq[wave][h * ROWP + c2 * 8]);
#pragma unroll
            for (int e = 0; e < 8; ++e)
                s = fmaf(bf2f((unsigned short)qv[e]), kf[c2 * 8 + e], s);
        }
        s *= 0.125f;

        float m = s;
#pragma unroll
        for (int o = 1; o < 16; o <<= 1) m = fmaxf(m, __shfl_xor(m, o, 64));
        float p = expf(s - m);
        float sum = p;
#pragma unroll
        for (int o = 1; o < 16; o <<= 1) sum += __shfl_xor(sum, o, 64);
        lp[wave][h * 16 + g] = p / sum;
    }
    __syncthreads();

    const int h = lane >> 2;
    const int db = (lane & 3) * 16;
    float o[16];
#pragma unroll
    for (int e = 0; e < 16; ++e) o[e] = 0.f;

    for (int g2 = 0; g2 < 16; ++g2) {
        const float pw = lp[wave][h * 16 + g2];
        short8 v0 = *reinterpret_cast<const short8*>(&lv[wave][g2 * ROWP + db]);
        short8 v1 = *reinterpret_cast<const short8*>(&lv[wave][g2 * ROWP + db + 8]);
#pragma unroll
        for (int e = 0; e < 8; ++e) {
            o[e]     = fmaf(pw, bf2f((unsigned short)v0[e]), o[e]);
            o[8 + e] = fmaf(pw, bf2f((unsigned short)v1[e]), o[8 + e]);
        }
    }

    short8 o0, o1;
#pragma unroll
    for (int e = 0; e < 8; ++e) {
        o0[e] = (short)f2bf(o[e]);
        o1[e] = (short)f2bf(o[8 + e]);
    }
    unsigned short* dst = O + (size_t)n * EMB + h * 64 + db;
    *reinterpret_cast<short8*>(dst) = o0;
    *reinterpret_cast<short8*>(dst + 8) = o1;
}

// ---------------- launch ----------------
extern "C" void kernel_launch(void* const* d_in, const int* in_sizes, int n_in,
                              void* d_out, int out_size, void* d_ws, size_t ws_size,
                              hipStream_t stream)
{
    const float* src = (const float*)d_in[0];
    const float* Wq  = (const float*)d_in[1];
    const float* bq  = (const float*)d_in[2];
    const float* Wk  = (const float*)d_in[3];
    const float* bk  = (const float*)d_in[4];
    const float* Wv  = (const float*)d_in[5];
    const float* bv  = (const float*)d_in[6];
    const float* Wo  = (const float*)d_in[7];
    const float* bo  = (const float*)d_in[8];
    float* out = (float*)d_out;

    unsigned short* ws = (unsigned short*)d_ws;
    unsigned short* src_bf = ws;                                      // 16384*1024
    unsigned short* wqkv   = src_bf + (size_t)NTOK * EMB;             // 3*1024*1024 (Wq|Wk|Wv)
    unsigned short* wo_bf  = wqkv + (size_t)3 * EMB * EMB;            // 1024*1024
    unsigned short* qkv    = wo_bf + (size_t)EMB * EMB;               // 16384*3072
    unsigned short* ab     = qkv + (size_t)NTOK * 3 * EMB;            // 16384*1024
    float* bias_cat        = (float*)(ab + (size_t)NTOK * EMB);       // 3072 floats

    // single conversion dispatch: src + 4 weights + bias concat
    cvt_all<<<2048, 256, 0, stream>>>(src, Wq, Wk, Wv, Wo, bq, bk, bv,
                                      src_bf, wqkv, bias_cat);

    // fused QKV projection: [16384][3072] = src_bf * (Wq|Wk|Wv)^T
    gemm8p<unsigned short><<<dim3(64 * 12), 512, 0, stream>>>(
        src_bf, wqkv, bias_cat, qkv, EMB, 3 * EMB, 64);

    attn_kernel<<<NTOK / 4, 256, 0, stream>>>(qkv, ab);

    // output projection: [16384][1024]
    gemm8p<float><<<dim3(64 * 4), 512, 0, stream>>>(
        ab, wo_bf, bo, out, EMB, EMB, 64);
}